// Round 6
// baseline (254.826 us; speedup 1.0000x reference)
//
#include <hip/hip_runtime.h>

// Conv2dFusion v3: wave-specialized fused pipeline, 2 blocks/CU.
// Per image: 128x128 rank-1 map -> conv0(1->32)+GELU+pool (VALU, H-table, GELU-after-max)
//   -> conv1(32->64)+GELU+pool (MFMA, waves 0-3) -> P1 6-row LDS ring
//   -> conv2(64->64)+GELU+pool (MFMA, waves 4-7, interleaved) -> out.
// LDS 65.7KB -> 2 blocks/CU; shared wf[18] frag array keeps VGPR <= 128.

typedef short short8 __attribute__((ext_vector_type(8)));
typedef float f32x4 __attribute__((ext_vector_type(4)));

#define OFF_TY   0                    // f32[128]
#define OFF_TK   512                  // f32[128]
#define OFF_HLO  1024                 // u32[32*126]
#define OFF_HHI  (1024 + 16128)       // u16[32*126]
#define OFF_P0   (17152 + 8064)       // 25216: 4 slots * 264 units * 16B
#define OFF_P1   (25216 + 16896)      // 42112: ring 6 rows*240 units + 32 pad = 1472 units
#define LDS_TOTAL (42112 + 1472*16)   // 65,664 B

__device__ __forceinline__ unsigned short f2bf(float f) {
    unsigned int u = __float_as_uint(f);
    u += 0x7fffu + ((u >> 16) & 1u);   // RNE
    return (unsigned short)(u >> 16);
}

// erf-GELU via A&S 7.1.25 (|err| <= 2.5e-5), branch-free.
__device__ __forceinline__ float gelu_f(float x) {
    float ax = __builtin_fabsf(x);
    float E  = __builtin_amdgcn_exp2f(x * x * -0.72134752f);
    float k  = __builtin_amdgcn_rcpf(__builtin_fmaf(0.33267686f, ax, 1.0f));
    float s  = __builtin_fmaf(0.7478556f, k, -0.0958798f);
    s = __builtin_fmaf(s, k, 0.3480242f);
    s = s * k;
    float erfabs = __builtin_fmaf(-s, E, 1.0f);
    return __builtin_fmaf(0.5f * ax, erfabs, 0.5f * x);
}

// pool0 producer: pooled rows R0, R0+1 into P0 ring (GELU applied after max).
__device__ __forceinline__ void produce(char* smem, const float* tys,
                                        float b0r, int c, int tid, int R0) {
    float t0 = tys[2*R0+0], t1 = tys[2*R0+1], t2 = tys[2*R0+2],
          t3 = tys[2*R0+3], t4 = tys[2*R0+4], t5 = tys[2*R0+5];
    int rest = tid >> 5;
    #pragma unroll
    for (int k = 0; k < 8; ++k, rest += 16) {
        if (rest < 126) {
            int roff = (rest >= 63) ? 1 : 0;
            int q = rest - (roff ? 63 : 0);
            float s0 = roff ? t2 : t0;
            float s1 = roff ? t3 : t1;
            float s2 = roff ? t4 : t2;
            float s3 = roff ? t5 : t3;
            uint2 lo = *(const uint2*)(smem + OFF_HLO + (c*126 + 2*q)*4);
            unsigned int hi = *(const unsigned int*)(smem + OFF_HHI + (c*126 + 2*q)*2);
            float h00 = __uint_as_float(lo.x << 16);
            float h10 = __uint_as_float(lo.x & 0xffff0000u);
            float h01 = __uint_as_float(lo.y << 16);
            float h11 = __uint_as_float(lo.y & 0xffff0000u);
            float h20 = __uint_as_float(hi << 16);
            float h21 = __uint_as_float(hi & 0xffff0000u);
            float e00 = __builtin_fmaf(s0,h00, __builtin_fmaf(s1,h10, __builtin_fmaf(s2,h20, b0r)));
            float e10 = __builtin_fmaf(s1,h00, __builtin_fmaf(s2,h10, __builtin_fmaf(s3,h20, b0r)));
            float e01 = __builtin_fmaf(s0,h01, __builtin_fmaf(s1,h11, __builtin_fmaf(s2,h21, b0r)));
            float e11 = __builtin_fmaf(s1,h01, __builtin_fmaf(s2,h11, __builtin_fmaf(s3,h21, b0r)));
            // GELU after max (monotone for x>-0.75; bias bounded & smoothed downstream)
            float m = gelu_f(fmaxf(fmaxf(e00, e01), fmaxf(e10, e11)));
            int slot = (R0 + roff) & 3;
            int unit = slot*264 + (q>>1)*8 + ((4*(q&1) + (c>>3)) ^ ((q>>1)&7));
            *(unsigned short*)(smem + OFF_P0 + unit*16 + (c&7)*2) = f2bf(m);
        }
    }
}

__launch_bounds__(512, 4)
__global__ void conv_pipeline(const float* __restrict__ token,
                              const float* __restrict__ type_,
                              const float* __restrict__ w0, const float* __restrict__ b0,
                              const float* __restrict__ w1, const float* __restrict__ b1,
                              const float* __restrict__ w2, const float* __restrict__ b2,
                              float* __restrict__ out) {
    extern __shared__ char smem[];
    float* tys = (float*)(smem + OFF_TY);
    float* tks = (float*)(smem + OFF_TK);

    const int tid = threadIdx.x;
    const int img = blockIdx.x;
    const int w   = tid >> 6;
    const int l   = tid & 63;
    const int l15 = l & 15;
    const int lc  = l >> 4;
    const int c0w = tid & 31;

    for (int i = tid; i < 128; i += 512) {
        tys[i] = type_[img*128 + i];
        tks[i] = token[img*128 + i];
    }

    float w0r[9];
    #pragma unroll
    for (int i = 0; i < 9; ++i) w0r[i] = w0[c0w*9 + i];
    const float b0r = b0[c0w];

    // Shared fragment storage: waves 0-3 use wf[0..8] (conv1, nt=w),
    // waves 4-7 use wf[0..17] (conv2, nt=w-4, kh*9+uv).
    short8 wf[18];
    float bias;
    const int ch = ((w & 3) * 16) + l15;       // c1 (waves<4) or c2 (waves>=4)
    if (w < 4) {
        bias = b1[ch];
        #pragma unroll
        for (int uv = 0; uv < 9; ++uv) {
            short8 f;
            #pragma unroll
            for (int j = 0; j < 8; ++j)
                f[j] = (short)f2bf(w1[(ch*32 + 8*lc + j)*9 + uv]);
            wf[uv] = f;
        }
    } else {
        bias = b2[ch];
        #pragma unroll
        for (int kh = 0; kh < 2; ++kh)
            #pragma unroll
            for (int uv = 0; uv < 9; ++uv) {
                short8 f;
                #pragma unroll
                for (int j = 0; j < 8; ++j)
                    f[j] = (short)f2bf(w2[(ch*64 + kh*32 + 8*lc + j)*9 + uv]);
                wf[kh*9 + uv] = f;
            }
    }

    __syncthreads();   // ty/tk visible

    // H[c][x][u] = sum_v w0[c,u,v]*tk[x+v]
    {
        int x = tid >> 5;
        #pragma unroll
        for (int k = 0; k < 8; ++k, x += 16) {
            if (x < 126) {
                float t0 = tks[x], t1 = tks[x+1], t2 = tks[x+2];
                float h0 = __builtin_fmaf(w0r[0],t0, __builtin_fmaf(w0r[1],t1, w0r[2]*t2));
                float h1 = __builtin_fmaf(w0r[3],t0, __builtin_fmaf(w0r[4],t1, w0r[5]*t2));
                float h2 = __builtin_fmaf(w0r[6],t0, __builtin_fmaf(w0r[7],t1, w0r[8]*t2));
                unsigned int lov = (unsigned int)f2bf(h0) | ((unsigned int)f2bf(h1) << 16);
                *(unsigned int*)(smem + OFF_HLO + (c0w*126 + x)*4) = lov;
                *(unsigned short*)(smem + OFF_HHI + (c0w*126 + x)*2) = f2bf(h2);
            }
        }
    }
    __syncthreads();   // H visible

    produce(smem, tys, b0r, c0w, tid, 0);
    produce(smem, tys, b0r, c0w, tid, 2);

    const size_t obase = (size_t)img * 12544;

    for (int i1 = 0; i1 < 30; ++i1) {
        __syncthreads();   // P0 strip + P1[i1-1] visible

        if (w < 4) {
            // ---------- conv1 row i1: waves 0-3, nt=w, all 4 mtiles ----------
            f32x4 acc[8];   // [mt][row]
            #pragma unroll
            for (int i = 0; i < 8; ++i) acc[i] = (f32x4){0.f,0.f,0.f,0.f};
            #pragma unroll
            for (int pr = 0; pr < 4; ++pr) {
                int sbase = ((2*i1 + pr) & 3) * 264;
                #pragma unroll
                for (int v = 0; v < 3; ++v) {
                    #pragma unroll
                    for (int mt = 0; mt < 4; ++mt) {
                        int col = mt*16 + l15 + v;
                        int unit = sbase + (col>>1)*8 + ((4*(col&1) + lc) ^ ((col>>1)&7));
                        short8 a = *(const short8*)(smem + OFF_P0 + unit*16);
                        if (pr <= 2)
                            acc[mt*2+0] = __builtin_amdgcn_mfma_f32_16x16x32_bf16(
                                a, wf[pr*3+v], acc[mt*2+0], 0, 0, 0);
                        if (pr >= 1)
                            acc[mt*2+1] = __builtin_amdgcn_mfma_f32_16x16x32_bf16(
                                a, wf[(pr-1)*3+v], acc[mt*2+1], 0, 0, 0);
                    }
                }
            }
            // epilogue: premax -> +bias -> GELU -> P1 ring row i1%6
            int rbase = (i1 % 6) * 30;
            int xr = ch >> 3;
            #pragma unroll
            for (int mt = 0; mt < 4; ++mt) {
                int pcol = mt*8 + lc*2;
                if (pcol < 30) {
                    f32x4 A0 = acc[mt*2+0], A1 = acc[mt*2+1];
                    float p0 = fmaxf(fmaxf(A0[0], A0[1]), fmaxf(A1[0], A1[1]));
                    float p1 = fmaxf(fmaxf(A0[2], A0[3]), fmaxf(A1[2], A1[3]));
                    float m0 = gelu_f(p0 + bias);
                    float m1 = gelu_f(p1 + bias);
                    int u0 = (rbase + pcol)*8     + (xr ^ (pcol & 7));
                    int u1 = (rbase + pcol + 1)*8 + (xr ^ ((pcol+1) & 7));
                    *(unsigned short*)(smem + OFF_P1 + u0*16 + (ch&7)*2) = f2bf(m0);
                    *(unsigned short*)(smem + OFF_P1 + u1*16 + (ch&7)*2) = f2bf(m1);
                }
            }
        } else if (i1 >= 4 && (i1 & 1) == 0) {
            // ---------- conv2 row i2: waves 4-7, nt=w-4, 2 mtiles ----------
            const int i2 = (i1 - 4) >> 1;
            f32x4 acc[4];   // [mt][row]
            #pragma unroll
            for (int i = 0; i < 4; ++i) acc[i] = (f32x4){0.f,0.f,0.f,0.f};
            #pragma unroll
            for (int pr = 0; pr < 4; ++pr) {
                int rb = ((2*i2 + pr) % 6) * 30;
                #pragma unroll
                for (int v = 0; v < 3; ++v) {
                    #pragma unroll
                    for (int mt = 0; mt < 2; ++mt) {
                        int col = mt*16 + l15 + v;
                        #pragma unroll
                        for (int kh = 0; kh < 2; ++kh) {
                            int unit = (rb + col)*8 + ((kh*4 + lc) ^ (col & 7));
                            short8 a = *(const short8*)(smem + OFF_P1 + unit*16);
                            if (pr <= 2)
                                acc[mt*2+0] = __builtin_amdgcn_mfma_f32_16x16x32_bf16(
                                    a, wf[kh*9 + pr*3+v], acc[mt*2+0], 0, 0, 0);
                            if (pr >= 1)
                                acc[mt*2+1] = __builtin_amdgcn_mfma_f32_16x16x32_bf16(
                                    a, wf[kh*9 + (pr-1)*3+v], acc[mt*2+1], 0, 0, 0);
                        }
                    }
                }
            }
            // epilogue: exact GELU x8 then max -> out
            #pragma unroll
            for (int mt = 0; mt < 2; ++mt) {
                int pcol = mt*8 + lc*2;
                if (pcol < 14) {
                    f32x4 A0 = acc[mt*2+0], A1 = acc[mt*2+1];
                    float g00 = gelu_f(A0[0] + bias), g01 = gelu_f(A0[1] + bias);
                    float g02 = gelu_f(A0[2] + bias), g03 = gelu_f(A0[3] + bias);
                    float g10 = gelu_f(A1[0] + bias), g11 = gelu_f(A1[1] + bias);
                    float g12 = gelu_f(A1[2] + bias), g13 = gelu_f(A1[3] + bias);
                    float m0 = fmaxf(fmaxf(g00, g01), fmaxf(g10, g11));
                    float m1 = fmaxf(fmaxf(g02, g03), fmaxf(g12, g13));
                    float2 st; st.x = m0; st.y = m1;
                    *(float2*)(out + obase + ch*196 + i2*14 + pcol) = st;
                }
            }
        }

        __syncthreads();   // conv1 reads of P0 done; P1 row i1 done
        if (i1 < 29) produce(smem, tys, b0r, c0w, tid, 2*i1 + 4);
    }

    __syncthreads();
    // tail: conv2 row 13 (P1 rows 26..29)
    if (w >= 4) {
        const int i2 = 13;
        f32x4 acc[4];
        #pragma unroll
        for (int i = 0; i < 4; ++i) acc[i] = (f32x4){0.f,0.f,0.f,0.f};
        #pragma unroll
        for (int pr = 0; pr < 4; ++pr) {
            int rb = ((2*i2 + pr) % 6) * 30;
            #pragma unroll
            for (int v = 0; v < 3; ++v) {
                #pragma unroll
                for (int mt = 0; mt < 2; ++mt) {
                    int col = mt*16 + l15 + v;
                    #pragma unroll
                    for (int kh = 0; kh < 2; ++kh) {
                        int unit = (rb + col)*8 + ((kh*4 + lc) ^ (col & 7));
                        short8 a = *(const short8*)(smem + OFF_P1 + unit*16);
                        if (pr <= 2)
                            acc[mt*2+0] = __builtin_amdgcn_mfma_f32_16x16x32_bf16(
                                a, wf[kh*9 + pr*3+v], acc[mt*2+0], 0, 0, 0);
                        if (pr >= 1)
                            acc[mt*2+1] = __builtin_amdgcn_mfma_f32_16x16x32_bf16(
                                a, wf[kh*9 + (pr-1)*3+v], acc[mt*2+1], 0, 0, 0);
                    }
                }
            }
        }
        #pragma unroll
        for (int mt = 0; mt < 2; ++mt) {
            int pcol = mt*8 + lc*2;
            if (pcol < 14) {
                f32x4 A0 = acc[mt*2+0], A1 = acc[mt*2+1];
                float g00 = gelu_f(A0[0] + bias), g01 = gelu_f(A0[1] + bias);
                float g02 = gelu_f(A0[2] + bias), g03 = gelu_f(A0[3] + bias);
                float g10 = gelu_f(A1[0] + bias), g11 = gelu_f(A1[1] + bias);
                float g12 = gelu_f(A1[2] + bias), g13 = gelu_f(A1[3] + bias);
                float m0 = fmaxf(fmaxf(g00, g01), fmaxf(g10, g11));
                float m1 = fmaxf(fmaxf(g02, g03), fmaxf(g12, g13));
                float2 st; st.x = m0; st.y = m1;
                *(float2*)(out + obase + ch*196 + i2*14 + pcol) = st;
            }
        }
    }
}

extern "C" void kernel_launch(void* const* d_in, const int* in_sizes, int n_in,
                              void* d_out, int out_size, void* d_ws, size_t ws_size,
                              hipStream_t stream) {
    const float* token = (const float*)d_in[0];
    const float* type_ = (const float*)d_in[1];
    const float* w0 = (const float*)d_in[2];
    const float* b0 = (const float*)d_in[3];
    const float* w1 = (const float*)d_in[4];
    const float* b1 = (const float*)d_in[5];
    const float* w2 = (const float*)d_in[6];
    const float* b2 = (const float*)d_in[7];
    float* out = (float*)d_out;

    hipLaunchKernelGGL(conv_pipeline, dim3(512), dim3(512), LDS_TOTAL, stream,
                       token, type_, w0, b0, w1, b1, w2, b2, out);
}

// Round 7
// 253.589 us; speedup vs baseline: 1.0049x; 1.0049x over previous
//
#include <hip/hip_runtime.h>

// Conv2dFusion v3: wave-specialized fused pipeline, 2 blocks/CU.
// Per image: 128x128 rank-1 map -> conv0(1->32)+GELU+pool (VALU, H-table, GELU-after-max)
//   -> conv1(32->64)+GELU+pool (MFMA, waves 0-3) -> P1 6-row LDS ring
//   -> conv2(64->64)+GELU+pool (MFMA, waves 4-7, interleaved) -> out.
// LDS 65.7KB -> 2 blocks/CU; shared wf[18] frag array keeps VGPR <= 128.

typedef short short8 __attribute__((ext_vector_type(8)));
typedef float f32x4 __attribute__((ext_vector_type(4)));

#define OFF_TY   0                    // f32[128]
#define OFF_TK   512                  // f32[128]
#define OFF_HLO  1024                 // u32[32*126]
#define OFF_HHI  (1024 + 16128)       // u16[32*126]
#define OFF_P0   (17152 + 8064)       // 25216: 4 slots * 264 units * 16B
#define OFF_P1   (25216 + 16896)      // 42112: ring 6 rows*240 units + 32 pad = 1472 units
#define LDS_TOTAL (42112 + 1472*16)   // 65,664 B

__device__ __forceinline__ unsigned short f2bf(float f) {
    unsigned int u = __float_as_uint(f);
    u += 0x7fffu + ((u >> 16) & 1u);   // RNE
    return (unsigned short)(u >> 16);
}

// erf-GELU via A&S 7.1.25 (|err| <= 2.5e-5), branch-free.
__device__ __forceinline__ float gelu_f(float x) {
    float ax = __builtin_fabsf(x);
    float E  = __builtin_amdgcn_exp2f(x * x * -0.72134752f);
    float k  = __builtin_amdgcn_rcpf(__builtin_fmaf(0.33267686f, ax, 1.0f));
    float s  = __builtin_fmaf(0.7478556f, k, -0.0958798f);
    s = __builtin_fmaf(s, k, 0.3480242f);
    s = s * k;
    float erfabs = __builtin_fmaf(-s, E, 1.0f);
    return __builtin_fmaf(0.5f * ax, erfabs, 0.5f * x);
}

// pool0 producer: pooled rows R0, R0+1 into P0 ring (GELU applied after max).
__device__ __forceinline__ void produce(char* smem, const float* tys,
                                        float b0r, int c, int tid, int R0) {
    float t0 = tys[2*R0+0], t1 = tys[2*R0+1], t2 = tys[2*R0+2],
          t3 = tys[2*R0+3], t4 = tys[2*R0+4], t5 = tys[2*R0+5];
    int rest = tid >> 5;
    #pragma unroll
    for (int k = 0; k < 8; ++k, rest += 16) {
        if (rest < 126) {
            int roff = (rest >= 63) ? 1 : 0;
            int q = rest - (roff ? 63 : 0);
            float s0 = roff ? t2 : t0;
            float s1 = roff ? t3 : t1;
            float s2 = roff ? t4 : t2;
            float s3 = roff ? t5 : t3;
            uint2 lo = *(const uint2*)(smem + OFF_HLO + (c*126 + 2*q)*4);
            unsigned int hi = *(const unsigned int*)(smem + OFF_HHI + (c*126 + 2*q)*2);
            float h00 = __uint_as_float(lo.x << 16);
            float h10 = __uint_as_float(lo.x & 0xffff0000u);
            float h01 = __uint_as_float(lo.y << 16);
            float h11 = __uint_as_float(lo.y & 0xffff0000u);
            float h20 = __uint_as_float(hi << 16);
            float h21 = __uint_as_float(hi & 0xffff0000u);
            float e00 = __builtin_fmaf(s0,h00, __builtin_fmaf(s1,h10, __builtin_fmaf(s2,h20, b0r)));
            float e10 = __builtin_fmaf(s1,h00, __builtin_fmaf(s2,h10, __builtin_fmaf(s3,h20, b0r)));
            float e01 = __builtin_fmaf(s0,h01, __builtin_fmaf(s1,h11, __builtin_fmaf(s2,h21, b0r)));
            float e11 = __builtin_fmaf(s1,h01, __builtin_fmaf(s2,h11, __builtin_fmaf(s3,h21, b0r)));
            // GELU after max (monotone for x>-0.75; bias bounded & smoothed downstream)
            float m = gelu_f(fmaxf(fmaxf(e00, e01), fmaxf(e10, e11)));
            int slot = (R0 + roff) & 3;
            int unit = slot*264 + (q>>1)*8 + ((4*(q&1) + (c>>3)) ^ ((q>>1)&7));
            *(unsigned short*)(smem + OFF_P0 + unit*16 + (c&7)*2) = f2bf(m);
        }
    }
}

__launch_bounds__(512, 4)
__global__ void conv_pipeline(const float* __restrict__ token,
                              const float* __restrict__ type_,
                              const float* __restrict__ w0, const float* __restrict__ b0,
                              const float* __restrict__ w1, const float* __restrict__ b1,
                              const float* __restrict__ w2, const float* __restrict__ b2,
                              float* __restrict__ out) {
    extern __shared__ char smem[];
    float* tys = (float*)(smem + OFF_TY);
    float* tks = (float*)(smem + OFF_TK);

    const int tid = threadIdx.x;
    const int img = blockIdx.x;
    const int w   = tid >> 6;
    const int l   = tid & 63;
    const int l15 = l & 15;
    const int lc  = l >> 4;
    const int c0w = tid & 31;

    for (int i = tid; i < 128; i += 512) {
        tys[i] = type_[img*128 + i];
        tks[i] = token[img*128 + i];
    }

    float w0r[9];
    #pragma unroll
    for (int i = 0; i < 9; ++i) w0r[i] = w0[c0w*9 + i];
    const float b0r = b0[c0w];

    // Shared fragment storage: waves 0-3 use wf[0..8] (conv1, nt=w),
    // waves 4-7 use wf[0..17] (conv2, nt=w-4, kh*9+uv).
    short8 wf[18];
    float bias;
    const int ch = ((w & 3) * 16) + l15;       // c1 (waves<4) or c2 (waves>=4)
    if (w < 4) {
        bias = b1[ch];
        #pragma unroll
        for (int uv = 0; uv < 9; ++uv) {
            short8 f;
            #pragma unroll
            for (int j = 0; j < 8; ++j)
                f[j] = (short)f2bf(w1[(ch*32 + 8*lc + j)*9 + uv]);
            wf[uv] = f;
        }
    } else {
        bias = b2[ch];
        #pragma unroll
        for (int kh = 0; kh < 2; ++kh)
            #pragma unroll
            for (int uv = 0; uv < 9; ++uv) {
                short8 f;
                #pragma unroll
                for (int j = 0; j < 8; ++j)
                    f[j] = (short)f2bf(w2[(ch*64 + kh*32 + 8*lc + j)*9 + uv]);
                wf[kh*9 + uv] = f;
            }
    }

    __syncthreads();   // ty/tk visible

    // H[c][x][u] = sum_v w0[c,u,v]*tk[x+v]
    {
        int x = tid >> 5;
        #pragma unroll
        for (int k = 0; k < 8; ++k, x += 16) {
            if (x < 126) {
                float t0 = tks[x], t1 = tks[x+1], t2 = tks[x+2];
                float h0 = __builtin_fmaf(w0r[0],t0, __builtin_fmaf(w0r[1],t1, w0r[2]*t2));
                float h1 = __builtin_fmaf(w0r[3],t0, __builtin_fmaf(w0r[4],t1, w0r[5]*t2));
                float h2 = __builtin_fmaf(w0r[6],t0, __builtin_fmaf(w0r[7],t1, w0r[8]*t2));
                unsigned int lov = (unsigned int)f2bf(h0) | ((unsigned int)f2bf(h1) << 16);
                *(unsigned int*)(smem + OFF_HLO + (c0w*126 + x)*4) = lov;
                *(unsigned short*)(smem + OFF_HHI + (c0w*126 + x)*2) = f2bf(h2);
            }
        }
    }
    __syncthreads();   // H visible

    produce(smem, tys, b0r, c0w, tid, 0);
    produce(smem, tys, b0r, c0w, tid, 2);

    const size_t obase = (size_t)img * 12544;

    for (int i1 = 0; i1 < 30; ++i1) {
        __syncthreads();   // P0 strip + P1[i1-1] visible

        if (w < 4) {
            // ---------- conv1 row i1: waves 0-3, nt=w, all 4 mtiles ----------
            f32x4 acc[8];   // [mt][row]
            #pragma unroll
            for (int i = 0; i < 8; ++i) acc[i] = (f32x4){0.f,0.f,0.f,0.f};
            #pragma unroll
            for (int pr = 0; pr < 4; ++pr) {
                int sbase = ((2*i1 + pr) & 3) * 264;
                #pragma unroll
                for (int v = 0; v < 3; ++v) {
                    #pragma unroll
                    for (int mt = 0; mt < 4; ++mt) {
                        int col = mt*16 + l15 + v;
                        int unit = sbase + (col>>1)*8 + ((4*(col&1) + lc) ^ ((col>>1)&7));
                        short8 a = *(const short8*)(smem + OFF_P0 + unit*16);
                        if (pr <= 2)
                            acc[mt*2+0] = __builtin_amdgcn_mfma_f32_16x16x32_bf16(
                                a, wf[pr*3+v], acc[mt*2+0], 0, 0, 0);
                        if (pr >= 1)
                            acc[mt*2+1] = __builtin_amdgcn_mfma_f32_16x16x32_bf16(
                                a, wf[(pr-1)*3+v], acc[mt*2+1], 0, 0, 0);
                    }
                }
            }
            // epilogue: premax -> +bias -> GELU -> P1 ring row i1%6
            int rbase = (i1 % 6) * 30;
            int xr = ch >> 3;
            #pragma unroll
            for (int mt = 0; mt < 4; ++mt) {
                int pcol = mt*8 + lc*2;
                if (pcol < 30) {
                    f32x4 A0 = acc[mt*2+0], A1 = acc[mt*2+1];
                    float p0 = fmaxf(fmaxf(A0[0], A0[1]), fmaxf(A1[0], A1[1]));
                    float p1 = fmaxf(fmaxf(A0[2], A0[3]), fmaxf(A1[2], A1[3]));
                    float m0 = gelu_f(p0 + bias);
                    float m1 = gelu_f(p1 + bias);
                    int u0 = (rbase + pcol)*8     + (xr ^ (pcol & 7));
                    int u1 = (rbase + pcol + 1)*8 + (xr ^ ((pcol+1) & 7));
                    *(unsigned short*)(smem + OFF_P1 + u0*16 + (ch&7)*2) = f2bf(m0);
                    *(unsigned short*)(smem + OFF_P1 + u1*16 + (ch&7)*2) = f2bf(m1);
                }
            }
        } else if (i1 >= 4 && (i1 & 1) == 0) {
            // ---------- conv2 row i2: waves 4-7, nt=w-4, 2 mtiles ----------
            const int i2 = (i1 - 4) >> 1;
            f32x4 acc[4];   // [mt][row]
            #pragma unroll
            for (int i = 0; i < 4; ++i) acc[i] = (f32x4){0.f,0.f,0.f,0.f};
            #pragma unroll
            for (int pr = 0; pr < 4; ++pr) {
                int rb = ((2*i2 + pr) % 6) * 30;
                #pragma unroll
                for (int v = 0; v < 3; ++v) {
                    #pragma unroll
                    for (int mt = 0; mt < 2; ++mt) {
                        int col = mt*16 + l15 + v;
                        #pragma unroll
                        for (int kh = 0; kh < 2; ++kh) {
                            int unit = (rb + col)*8 + ((kh*4 + lc) ^ (col & 7));
                            short8 a = *(const short8*)(smem + OFF_P1 + unit*16);
                            if (pr <= 2)
                                acc[mt*2+0] = __builtin_amdgcn_mfma_f32_16x16x32_bf16(
                                    a, wf[kh*9 + pr*3+v], acc[mt*2+0], 0, 0, 0);
                            if (pr >= 1)
                                acc[mt*2+1] = __builtin_amdgcn_mfma_f32_16x16x32_bf16(
                                    a, wf[kh*9 + (pr-1)*3+v], acc[mt*2+1], 0, 0, 0);
                        }
                    }
                }
            }
            // epilogue: exact GELU x8 then max -> out
            #pragma unroll
            for (int mt = 0; mt < 2; ++mt) {
                int pcol = mt*8 + lc*2;
                if (pcol < 14) {
                    f32x4 A0 = acc[mt*2+0], A1 = acc[mt*2+1];
                    float g00 = gelu_f(A0[0] + bias), g01 = gelu_f(A0[1] + bias);
                    float g02 = gelu_f(A0[2] + bias), g03 = gelu_f(A0[3] + bias);
                    float g10 = gelu_f(A1[0] + bias), g11 = gelu_f(A1[1] + bias);
                    float g12 = gelu_f(A1[2] + bias), g13 = gelu_f(A1[3] + bias);
                    float m0 = fmaxf(fmaxf(g00, g01), fmaxf(g10, g11));
                    float m1 = fmaxf(fmaxf(g02, g03), fmaxf(g12, g13));
                    float2 st; st.x = m0; st.y = m1;
                    *(float2*)(out + obase + ch*196 + i2*14 + pcol) = st;
                }
            }
        }

        __syncthreads();   // conv1 reads of P0 done; P1 row i1 done
        if (i1 < 29) produce(smem, tys, b0r, c0w, tid, 2*i1 + 4);
    }

    __syncthreads();
    // tail: conv2 row 13 (P1 rows 26..29)
    if (w >= 4) {
        const int i2 = 13;
        f32x4 acc[4];
        #pragma unroll
        for (int i = 0; i < 4; ++i) acc[i] = (f32x4){0.f,0.f,0.f,0.f};
        #pragma unroll
        for (int pr = 0; pr < 4; ++pr) {
            int rb = ((2*i2 + pr) % 6) * 30;
            #pragma unroll
            for (int v = 0; v < 3; ++v) {
                #pragma unroll
                for (int mt = 0; mt < 2; ++mt) {
                    int col = mt*16 + l15 + v;
                    #pragma unroll
                    for (int kh = 0; kh < 2; ++kh) {
                        int unit = (rb + col)*8 + ((kh*4 + lc) ^ (col & 7));
                        short8 a = *(const short8*)(smem + OFF_P1 + unit*16);
                        if (pr <= 2)
                            acc[mt*2+0] = __builtin_amdgcn_mfma_f32_16x16x32_bf16(
                                a, wf[kh*9 + pr*3+v], acc[mt*2+0], 0, 0, 0);
                        if (pr >= 1)
                            acc[mt*2+1] = __builtin_amdgcn_mfma_f32_16x16x32_bf16(
                                a, wf[kh*9 + (pr-1)*3+v], acc[mt*2+1], 0, 0, 0);
                    }
                }
            }
        }
        #pragma unroll
        for (int mt = 0; mt < 2; ++mt) {
            int pcol = mt*8 + lc*2;
            if (pcol < 14) {
                f32x4 A0 = acc[mt*2+0], A1 = acc[mt*2+1];
                float g00 = gelu_f(A0[0] + bias), g01 = gelu_f(A0[1] + bias);
                float g02 = gelu_f(A0[2] + bias), g03 = gelu_f(A0[3] + bias);
                float g10 = gelu_f(A1[0] + bias), g11 = gelu_f(A1[1] + bias);
                float g12 = gelu_f(A1[2] + bias), g13 = gelu_f(A1[3] + bias);
                float m0 = fmaxf(fmaxf(g00, g01), fmaxf(g10, g11));
                float m1 = fmaxf(fmaxf(g02, g03), fmaxf(g12, g13));
                float2 st; st.x = m0; st.y = m1;
                *(float2*)(out + obase + ch*196 + i2*14 + pcol) = st;
            }
        }
    }
}

extern "C" void kernel_launch(void* const* d_in, const int* in_sizes, int n_in,
                              void* d_out, int out_size, void* d_ws, size_t ws_size,
                              hipStream_t stream) {
    const float* token = (const float*)d_in[0];
    const float* type_ = (const float*)d_in[1];
    const float* w0 = (const float*)d_in[2];
    const float* b0 = (const float*)d_in[3];
    const float* w1 = (const float*)d_in[4];
    const float* b1 = (const float*)d_in[5];
    const float* w2 = (const float*)d_in[6];
    const float* b2 = (const float*)d_in[7];
    float* out = (float*)d_out;

    hipLaunchKernelGGL(conv_pipeline, dim3(512), dim3(512), LDS_TOTAL, stream,
                       token, type_, w0, b0, w1, b1, w2, b2, out);
}

// Round 8
// 196.037 us; speedup vs baseline: 1.2999x; 1.2936x over previous
//
#include <hip/hip_runtime.h>

// Conv2dFusion v4: wave-specialized fused pipeline, 2 blocks/CU.
// Per image: 128x128 rank-1 map -> conv0(1->32)+GELU+pool (VALU, H-table, GELU-after-max)
//   -> conv1(32->64)+GELU+pool (MFMA, waves 0-3) -> P1 6-row LDS ring
//   -> conv2(64->64)+GELU+pool (MFMA, waves 4-7, interleaved) -> out.
// v4 fix: __launch_bounds__(512, 2) -- the 2nd arg is CUDA-style min BLOCKS/CU.
// (512,4) forced a 64-VGPR cap -> wf[18] (72 VGPR) spilled to scratch ->
// 345 MB/dispatch of spill traffic. (512,2) = 4 waves/SIMD = 128-VGPR cap,
// matching the LDS limit (65.6 KB -> 2 blocks/CU), fragments stay in registers.

typedef short short8 __attribute__((ext_vector_type(8)));
typedef float f32x4 __attribute__((ext_vector_type(4)));

#define OFF_TY   0                    // f32[128]
#define OFF_TK   512                  // f32[128]
#define OFF_HLO  1024                 // u32[32*126]
#define OFF_HHI  (1024 + 16128)       // u16[32*126]
#define OFF_P0   (17152 + 8064)       // 25216: 4 slots * 264 units * 16B
#define OFF_P1   (25216 + 16896)      // 42112: ring 6 rows*240 units + 32 pad = 1472 units
#define LDS_TOTAL (42112 + 1472*16)   // 65,664 B

__device__ __forceinline__ unsigned short f2bf(float f) {
    unsigned int u = __float_as_uint(f);
    u += 0x7fffu + ((u >> 16) & 1u);   // RNE
    return (unsigned short)(u >> 16);
}

// erf-GELU via A&S 7.1.25 (|err| <= 2.5e-5), branch-free.
__device__ __forceinline__ float gelu_f(float x) {
    float ax = __builtin_fabsf(x);
    float E  = __builtin_amdgcn_exp2f(x * x * -0.72134752f);
    float k  = __builtin_amdgcn_rcpf(__builtin_fmaf(0.33267686f, ax, 1.0f));
    float s  = __builtin_fmaf(0.7478556f, k, -0.0958798f);
    s = __builtin_fmaf(s, k, 0.3480242f);
    s = s * k;
    float erfabs = __builtin_fmaf(-s, E, 1.0f);
    return __builtin_fmaf(0.5f * ax, erfabs, 0.5f * x);
}

// pool0 producer: pooled rows R0, R0+1 into P0 ring (GELU applied after max).
__device__ __forceinline__ void produce(char* smem, const float* tys,
                                        float b0r, int c, int tid, int R0) {
    float t0 = tys[2*R0+0], t1 = tys[2*R0+1], t2 = tys[2*R0+2],
          t3 = tys[2*R0+3], t4 = tys[2*R0+4], t5 = tys[2*R0+5];
    int rest = tid >> 5;
    #pragma unroll
    for (int k = 0; k < 8; ++k, rest += 16) {
        if (rest < 126) {
            int roff = (rest >= 63) ? 1 : 0;
            int q = rest - (roff ? 63 : 0);
            float s0 = roff ? t2 : t0;
            float s1 = roff ? t3 : t1;
            float s2 = roff ? t4 : t2;
            float s3 = roff ? t5 : t3;
            uint2 lo = *(const uint2*)(smem + OFF_HLO + (c*126 + 2*q)*4);
            unsigned int hi = *(const unsigned int*)(smem + OFF_HHI + (c*126 + 2*q)*2);
            float h00 = __uint_as_float(lo.x << 16);
            float h10 = __uint_as_float(lo.x & 0xffff0000u);
            float h01 = __uint_as_float(lo.y << 16);
            float h11 = __uint_as_float(lo.y & 0xffff0000u);
            float h20 = __uint_as_float(hi << 16);
            float h21 = __uint_as_float(hi & 0xffff0000u);
            float e00 = __builtin_fmaf(s0,h00, __builtin_fmaf(s1,h10, __builtin_fmaf(s2,h20, b0r)));
            float e10 = __builtin_fmaf(s1,h00, __builtin_fmaf(s2,h10, __builtin_fmaf(s3,h20, b0r)));
            float e01 = __builtin_fmaf(s0,h01, __builtin_fmaf(s1,h11, __builtin_fmaf(s2,h21, b0r)));
            float e11 = __builtin_fmaf(s1,h01, __builtin_fmaf(s2,h11, __builtin_fmaf(s3,h21, b0r)));
            // GELU after max (monotone for x>-0.75; bias bounded & smoothed downstream)
            float m = gelu_f(fmaxf(fmaxf(e00, e01), fmaxf(e10, e11)));
            int slot = (R0 + roff) & 3;
            int unit = slot*264 + (q>>1)*8 + ((4*(q&1) + (c>>3)) ^ ((q>>1)&7));
            *(unsigned short*)(smem + OFF_P0 + unit*16 + (c&7)*2) = f2bf(m);
        }
    }
}

__launch_bounds__(512, 2)
__global__ void conv_pipeline(const float* __restrict__ token,
                              const float* __restrict__ type_,
                              const float* __restrict__ w0, const float* __restrict__ b0,
                              const float* __restrict__ w1, const float* __restrict__ b1,
                              const float* __restrict__ w2, const float* __restrict__ b2,
                              float* __restrict__ out) {
    extern __shared__ char smem[];
    float* tys = (float*)(smem + OFF_TY);
    float* tks = (float*)(smem + OFF_TK);

    const int tid = threadIdx.x;
    const int img = blockIdx.x;
    const int w   = tid >> 6;
    const int l   = tid & 63;
    const int l15 = l & 15;
    const int lc  = l >> 4;
    const int c0w = tid & 31;

    for (int i = tid; i < 128; i += 512) {
        tys[i] = type_[img*128 + i];
        tks[i] = token[img*128 + i];
    }

    float w0r[9];
    #pragma unroll
    for (int i = 0; i < 9; ++i) w0r[i] = w0[c0w*9 + i];
    const float b0r = b0[c0w];

    // Shared fragment storage: waves 0-3 use wf[0..8] (conv1, nt=w),
    // waves 4-7 use wf[0..17] (conv2, nt=w-4, kh*9+uv).
    short8 wf[18];
    float bias;
    const int ch = ((w & 3) * 16) + l15;       // c1 (waves<4) or c2 (waves>=4)
    if (w < 4) {
        bias = b1[ch];
        #pragma unroll
        for (int uv = 0; uv < 9; ++uv) {
            short8 f;
            #pragma unroll
            for (int j = 0; j < 8; ++j)
                f[j] = (short)f2bf(w1[(ch*32 + 8*lc + j)*9 + uv]);
            wf[uv] = f;
        }
    } else {
        bias = b2[ch];
        #pragma unroll
        for (int kh = 0; kh < 2; ++kh)
            #pragma unroll
            for (int uv = 0; uv < 9; ++uv) {
                short8 f;
                #pragma unroll
                for (int j = 0; j < 8; ++j)
                    f[j] = (short)f2bf(w2[(ch*64 + kh*32 + 8*lc + j)*9 + uv]);
                wf[kh*9 + uv] = f;
            }
    }

    __syncthreads();   // ty/tk visible

    // H[c][x][u] = sum_v w0[c,u,v]*tk[x+v]
    {
        int x = tid >> 5;
        #pragma unroll
        for (int k = 0; k < 8; ++k, x += 16) {
            if (x < 126) {
                float t0 = tks[x], t1 = tks[x+1], t2 = tks[x+2];
                float h0 = __builtin_fmaf(w0r[0],t0, __builtin_fmaf(w0r[1],t1, w0r[2]*t2));
                float h1 = __builtin_fmaf(w0r[3],t0, __builtin_fmaf(w0r[4],t1, w0r[5]*t2));
                float h2 = __builtin_fmaf(w0r[6],t0, __builtin_fmaf(w0r[7],t1, w0r[8]*t2));
                unsigned int lov = (unsigned int)f2bf(h0) | ((unsigned int)f2bf(h1) << 16);
                *(unsigned int*)(smem + OFF_HLO + (c0w*126 + x)*4) = lov;
                *(unsigned short*)(smem + OFF_HHI + (c0w*126 + x)*2) = f2bf(h2);
            }
        }
    }
    __syncthreads();   // H visible

    produce(smem, tys, b0r, c0w, tid, 0);
    produce(smem, tys, b0r, c0w, tid, 2);

    const size_t obase = (size_t)img * 12544;

    for (int i1 = 0; i1 < 30; ++i1) {
        __syncthreads();   // P0 strip + P1[i1-1] visible

        if (w < 4) {
            // ---------- conv1 row i1: waves 0-3, nt=w, all 4 mtiles ----------
            f32x4 acc[8];   // [mt][row]
            #pragma unroll
            for (int i = 0; i < 8; ++i) acc[i] = (f32x4){0.f,0.f,0.f,0.f};
            #pragma unroll
            for (int pr = 0; pr < 4; ++pr) {
                int sbase = ((2*i1 + pr) & 3) * 264;
                #pragma unroll
                for (int v = 0; v < 3; ++v) {
                    #pragma unroll
                    for (int mt = 0; mt < 4; ++mt) {
                        int col = mt*16 + l15 + v;
                        int unit = sbase + (col>>1)*8 + ((4*(col&1) + lc) ^ ((col>>1)&7));
                        short8 a = *(const short8*)(smem + OFF_P0 + unit*16);
                        if (pr <= 2)
                            acc[mt*2+0] = __builtin_amdgcn_mfma_f32_16x16x32_bf16(
                                a, wf[pr*3+v], acc[mt*2+0], 0, 0, 0);
                        if (pr >= 1)
                            acc[mt*2+1] = __builtin_amdgcn_mfma_f32_16x16x32_bf16(
                                a, wf[(pr-1)*3+v], acc[mt*2+1], 0, 0, 0);
                    }
                }
            }
            // epilogue: premax -> +bias -> GELU -> P1 ring row i1%6
            int rbase = (i1 % 6) * 30;
            int xr = ch >> 3;
            #pragma unroll
            for (int mt = 0; mt < 4; ++mt) {
                int pcol = mt*8 + lc*2;
                if (pcol < 30) {
                    f32x4 A0 = acc[mt*2+0], A1 = acc[mt*2+1];
                    float p0 = fmaxf(fmaxf(A0[0], A0[1]), fmaxf(A1[0], A1[1]));
                    float p1 = fmaxf(fmaxf(A0[2], A0[3]), fmaxf(A1[2], A1[3]));
                    float m0 = gelu_f(p0 + bias);
                    float m1 = gelu_f(p1 + bias);
                    int u0 = (rbase + pcol)*8     + (xr ^ (pcol & 7));
                    int u1 = (rbase + pcol + 1)*8 + (xr ^ ((pcol+1) & 7));
                    *(unsigned short*)(smem + OFF_P1 + u0*16 + (ch&7)*2) = f2bf(m0);
                    *(unsigned short*)(smem + OFF_P1 + u1*16 + (ch&7)*2) = f2bf(m1);
                }
            }
        } else if (i1 >= 4 && (i1 & 1) == 0) {
            // ---------- conv2 row i2: waves 4-7, nt=w-4, 2 mtiles ----------
            const int i2 = (i1 - 4) >> 1;
            f32x4 acc[4];   // [mt][row]
            #pragma unroll
            for (int i = 0; i < 4; ++i) acc[i] = (f32x4){0.f,0.f,0.f,0.f};
            #pragma unroll
            for (int pr = 0; pr < 4; ++pr) {
                int rb = ((2*i2 + pr) % 6) * 30;
                #pragma unroll
                for (int v = 0; v < 3; ++v) {
                    #pragma unroll
                    for (int mt = 0; mt < 2; ++mt) {
                        int col = mt*16 + l15 + v;
                        #pragma unroll
                        for (int kh = 0; kh < 2; ++kh) {
                            int unit = (rb + col)*8 + ((kh*4 + lc) ^ (col & 7));
                            short8 a = *(const short8*)(smem + OFF_P1 + unit*16);
                            if (pr <= 2)
                                acc[mt*2+0] = __builtin_amdgcn_mfma_f32_16x16x32_bf16(
                                    a, wf[kh*9 + pr*3+v], acc[mt*2+0], 0, 0, 0);
                            if (pr >= 1)
                                acc[mt*2+1] = __builtin_amdgcn_mfma_f32_16x16x32_bf16(
                                    a, wf[kh*9 + (pr-1)*3+v], acc[mt*2+1], 0, 0, 0);
                        }
                    }
                }
            }
            // epilogue: exact GELU x8 then max -> out
            #pragma unroll
            for (int mt = 0; mt < 2; ++mt) {
                int pcol = mt*8 + lc*2;
                if (pcol < 14) {
                    f32x4 A0 = acc[mt*2+0], A1 = acc[mt*2+1];
                    float g00 = gelu_f(A0[0] + bias), g01 = gelu_f(A0[1] + bias);
                    float g02 = gelu_f(A0[2] + bias), g03 = gelu_f(A0[3] + bias);
                    float g10 = gelu_f(A1[0] + bias), g11 = gelu_f(A1[1] + bias);
                    float g12 = gelu_f(A1[2] + bias), g13 = gelu_f(A1[3] + bias);
                    float m0 = fmaxf(fmaxf(g00, g01), fmaxf(g10, g11));
                    float m1 = fmaxf(fmaxf(g02, g03), fmaxf(g12, g13));
                    float2 st; st.x = m0; st.y = m1;
                    *(float2*)(out + obase + ch*196 + i2*14 + pcol) = st;
                }
            }
        }

        __syncthreads();   // conv1 reads of P0 done; P1 row i1 done
        if (i1 < 29) produce(smem, tys, b0r, c0w, tid, 2*i1 + 4);
    }

    __syncthreads();
    // tail: conv2 row 13 (P1 rows 26..29)
    if (w >= 4) {
        const int i2 = 13;
        f32x4 acc[4];
        #pragma unroll
        for (int i = 0; i < 4; ++i) acc[i] = (f32x4){0.f,0.f,0.f,0.f};
        #pragma unroll
        for (int pr = 0; pr < 4; ++pr) {
            int rb = ((2*i2 + pr) % 6) * 30;
            #pragma unroll
            for (int v = 0; v < 3; ++v) {
                #pragma unroll
                for (int mt = 0; mt < 2; ++mt) {
                    int col = mt*16 + l15 + v;
                    #pragma unroll
                    for (int kh = 0; kh < 2; ++kh) {
                        int unit = (rb + col)*8 + ((kh*4 + lc) ^ (col & 7));
                        short8 a = *(const short8*)(smem + OFF_P1 + unit*16);
                        if (pr <= 2)
                            acc[mt*2+0] = __builtin_amdgcn_mfma_f32_16x16x32_bf16(
                                a, wf[kh*9 + pr*3+v], acc[mt*2+0], 0, 0, 0);
                        if (pr >= 1)
                            acc[mt*2+1] = __builtin_amdgcn_mfma_f32_16x16x32_bf16(
                                a, wf[kh*9 + (pr-1)*3+v], acc[mt*2+1], 0, 0, 0);
                    }
                }
            }
        }
        #pragma unroll
        for (int mt = 0; mt < 2; ++mt) {
            int pcol = mt*8 + lc*2;
            if (pcol < 14) {
                f32x4 A0 = acc[mt*2+0], A1 = acc[mt*2+1];
                float g00 = gelu_f(A0[0] + bias), g01 = gelu_f(A0[1] + bias);
                float g02 = gelu_f(A0[2] + bias), g03 = gelu_f(A0[3] + bias);
                float g10 = gelu_f(A1[0] + bias), g11 = gelu_f(A1[1] + bias);
                float g12 = gelu_f(A1[2] + bias), g13 = gelu_f(A1[3] + bias);
                float m0 = fmaxf(fmaxf(g00, g01), fmaxf(g10, g11));
                float m1 = fmaxf(fmaxf(g02, g03), fmaxf(g12, g13));
                float2 st; st.x = m0; st.y = m1;
                *(float2*)(out + obase + ch*196 + i2*14 + pcol) = st;
            }
        }
    }
}

extern "C" void kernel_launch(void* const* d_in, const int* in_sizes, int n_in,
                              void* d_out, int out_size, void* d_ws, size_t ws_size,
                              hipStream_t stream) {
    const float* token = (const float*)d_in[0];
    const float* type_ = (const float*)d_in[1];
    const float* w0 = (const float*)d_in[2];
    const float* b0 = (const float*)d_in[3];
    const float* w1 = (const float*)d_in[4];
    const float* b1 = (const float*)d_in[5];
    const float* w2 = (const float*)d_in[6];
    const float* b2 = (const float*)d_in[7];
    float* out = (float*)d_out;

    hipLaunchKernelGGL(conv_pipeline, dim3(512), dim3(512), LDS_TOTAL, stream,
                       token, type_, w0, b0, w1, b1, w2, b2, out);
}

// Round 9
// 194.099 us; speedup vs baseline: 1.3129x; 1.0100x over previous
//
#include <hip/hip_runtime.h>

// Conv2dFusion v5: wave-specialized fused pipeline, targeting 2 blocks/CU.
// Per image: 128x128 rank-1 map -> conv0(1->32)+GELU+pool (VALU, H-table, GELU-after-max)
//   -> conv1(32->64)+GELU+pool (MFMA, waves 0-3) -> P1 6-row LDS ring
//   -> conv2(64->64)+GELU+pool (MFMA, waves 4-7, interleaved) -> out.
// v5: register diet to fit 4 waves/SIMD (2 blocks/CU):
//   (a) conv1 runs as two mt-pair passes with acc[4] (peak acc 32->16 regs,
//       same LDS reads, same per-output FMA order -> bit-identical),
//   (b) H-table built BEFORE wf[] fragment load so w0r(9) and wf(72) liveness
//       never overlap.
// v4 lesson kept: __launch_bounds__(512,2) == CUDA-style min-blocks semantics;
// (512,4) capped at 64 VGPR and spilled 345 MB/dispatch to scratch.

typedef short short8 __attribute__((ext_vector_type(8)));
typedef float f32x4 __attribute__((ext_vector_type(4)));

#define OFF_TY   0                    // f32[128]
#define OFF_TK   512                  // f32[128]
#define OFF_HLO  1024                 // u32[32*126]
#define OFF_HHI  (1024 + 16128)       // u16[32*126]
#define OFF_P0   (17152 + 8064)       // 25216: 4 slots * 264 units * 16B
#define OFF_P1   (25216 + 16896)      // 42112: ring 6 rows*240 units + 32 pad = 1472 units
#define LDS_TOTAL (42112 + 1472*16)   // 65,664 B

__device__ __forceinline__ unsigned short f2bf(float f) {
    unsigned int u = __float_as_uint(f);
    u += 0x7fffu + ((u >> 16) & 1u);   // RNE
    return (unsigned short)(u >> 16);
}

// erf-GELU via A&S 7.1.25 (|err| <= 2.5e-5), branch-free.
__device__ __forceinline__ float gelu_f(float x) {
    float ax = __builtin_fabsf(x);
    float E  = __builtin_amdgcn_exp2f(x * x * -0.72134752f);
    float k  = __builtin_amdgcn_rcpf(__builtin_fmaf(0.33267686f, ax, 1.0f));
    float s  = __builtin_fmaf(0.7478556f, k, -0.0958798f);
    s = __builtin_fmaf(s, k, 0.3480242f);
    s = s * k;
    float erfabs = __builtin_fmaf(-s, E, 1.0f);
    return __builtin_fmaf(0.5f * ax, erfabs, 0.5f * x);
}

// pool0 producer: pooled rows R0, R0+1 into P0 ring (GELU applied after max).
__device__ __forceinline__ void produce(char* smem, const float* tys,
                                        float b0r, int c, int tid, int R0) {
    float t0 = tys[2*R0+0], t1 = tys[2*R0+1], t2 = tys[2*R0+2],
          t3 = tys[2*R0+3], t4 = tys[2*R0+4], t5 = tys[2*R0+5];
    int rest = tid >> 5;
    #pragma unroll
    for (int k = 0; k < 8; ++k, rest += 16) {
        if (rest < 126) {
            int roff = (rest >= 63) ? 1 : 0;
            int q = rest - (roff ? 63 : 0);
            float s0 = roff ? t2 : t0;
            float s1 = roff ? t3 : t1;
            float s2 = roff ? t4 : t2;
            float s3 = roff ? t5 : t3;
            uint2 lo = *(const uint2*)(smem + OFF_HLO + (c*126 + 2*q)*4);
            unsigned int hi = *(const unsigned int*)(smem + OFF_HHI + (c*126 + 2*q)*2);
            float h00 = __uint_as_float(lo.x << 16);
            float h10 = __uint_as_float(lo.x & 0xffff0000u);
            float h01 = __uint_as_float(lo.y << 16);
            float h11 = __uint_as_float(lo.y & 0xffff0000u);
            float h20 = __uint_as_float(hi << 16);
            float h21 = __uint_as_float(hi & 0xffff0000u);
            float e00 = __builtin_fmaf(s0,h00, __builtin_fmaf(s1,h10, __builtin_fmaf(s2,h20, b0r)));
            float e10 = __builtin_fmaf(s1,h00, __builtin_fmaf(s2,h10, __builtin_fmaf(s3,h20, b0r)));
            float e01 = __builtin_fmaf(s0,h01, __builtin_fmaf(s1,h11, __builtin_fmaf(s2,h21, b0r)));
            float e11 = __builtin_fmaf(s1,h01, __builtin_fmaf(s2,h11, __builtin_fmaf(s3,h21, b0r)));
            // GELU after max (monotone for x>-0.75; bias bounded & smoothed downstream)
            float m = gelu_f(fmaxf(fmaxf(e00, e01), fmaxf(e10, e11)));
            int slot = (R0 + roff) & 3;
            int unit = slot*264 + (q>>1)*8 + ((4*(q&1) + (c>>3)) ^ ((q>>1)&7));
            *(unsigned short*)(smem + OFF_P0 + unit*16 + (c&7)*2) = f2bf(m);
        }
    }
}

__launch_bounds__(512, 2)
__global__ void conv_pipeline(const float* __restrict__ token,
                              const float* __restrict__ type_,
                              const float* __restrict__ w0, const float* __restrict__ b0,
                              const float* __restrict__ w1, const float* __restrict__ b1,
                              const float* __restrict__ w2, const float* __restrict__ b2,
                              float* __restrict__ out) {
    extern __shared__ char smem[];
    float* tys = (float*)(smem + OFF_TY);
    float* tks = (float*)(smem + OFF_TK);

    const int tid = threadIdx.x;
    const int img = blockIdx.x;
    const int w   = tid >> 6;
    const int l   = tid & 63;
    const int l15 = l & 15;
    const int lc  = l >> 4;
    const int c0w = tid & 31;

    for (int i = tid; i < 128; i += 512) {
        tys[i] = type_[img*128 + i];
        tks[i] = token[img*128 + i];
    }

    const float b0r = b0[c0w];

    __syncthreads();   // ty/tk visible

    // H[c][x][u] = sum_v w0[c,u,v]*tk[x+v]  (w0r lives only in this scope,
    // so its 9 regs are dead before wf[] is loaded)
    {
        float w0r[9];
        #pragma unroll
        for (int i = 0; i < 9; ++i) w0r[i] = w0[c0w*9 + i];
        int x = tid >> 5;
        #pragma unroll
        for (int k = 0; k < 8; ++k, x += 16) {
            if (x < 126) {
                float t0 = tks[x], t1 = tks[x+1], t2 = tks[x+2];
                float h0 = __builtin_fmaf(w0r[0],t0, __builtin_fmaf(w0r[1],t1, w0r[2]*t2));
                float h1 = __builtin_fmaf(w0r[3],t0, __builtin_fmaf(w0r[4],t1, w0r[5]*t2));
                float h2 = __builtin_fmaf(w0r[6],t0, __builtin_fmaf(w0r[7],t1, w0r[8]*t2));
                unsigned int lov = (unsigned int)f2bf(h0) | ((unsigned int)f2bf(h1) << 16);
                *(unsigned int*)(smem + OFF_HLO + (c0w*126 + x)*4) = lov;
                *(unsigned short*)(smem + OFF_HHI + (c0w*126 + x)*2) = f2bf(h2);
            }
        }
    }

    // Shared fragment storage: waves 0-3 use wf[0..8] (conv1, nt=w),
    // waves 4-7 use wf[0..17] (conv2, nt=w-4, kh*9+uv).
    short8 wf[18];
    float bias;
    const int ch = ((w & 3) * 16) + l15;       // c1 (waves<4) or c2 (waves>=4)
    if (w < 4) {
        bias = b1[ch];
        #pragma unroll
        for (int uv = 0; uv < 9; ++uv) {
            short8 f;
            #pragma unroll
            for (int j = 0; j < 8; ++j)
                f[j] = (short)f2bf(w1[(ch*32 + 8*lc + j)*9 + uv]);
            wf[uv] = f;
        }
    } else {
        bias = b2[ch];
        #pragma unroll
        for (int kh = 0; kh < 2; ++kh)
            #pragma unroll
            for (int uv = 0; uv < 9; ++uv) {
                short8 f;
                #pragma unroll
                for (int j = 0; j < 8; ++j)
                    f[j] = (short)f2bf(w2[(ch*64 + kh*32 + 8*lc + j)*9 + uv]);
                wf[kh*9 + uv] = f;
            }
    }

    __syncthreads();   // H visible

    produce(smem, tys, b0r, c0w, tid, 0);
    produce(smem, tys, b0r, c0w, tid, 2);

    const size_t obase = (size_t)img * 12544;

    for (int i1 = 0; i1 < 30; ++i1) {
        __syncthreads();   // P0 strip + P1[i1-1] visible

        if (w < 4) {
            // ---------- conv1 row i1: waves 0-3, nt=w, 2 passes of 2 mtiles ----------
            // (acc[4] per pass keeps peak accumulator liveness at 16 regs)
            int rbase = (i1 % 6) * 30;
            int xr = ch >> 3;
            #pragma unroll
            for (int half = 0; half < 2; ++half) {
                f32x4 acc[4];   // [mt_local][row]
                #pragma unroll
                for (int i = 0; i < 4; ++i) acc[i] = (f32x4){0.f,0.f,0.f,0.f};
                #pragma unroll
                for (int pr = 0; pr < 4; ++pr) {
                    int sbase = ((2*i1 + pr) & 3) * 264;
                    #pragma unroll
                    for (int v = 0; v < 3; ++v) {
                        #pragma unroll
                        for (int mtl = 0; mtl < 2; ++mtl) {
                            int col = (2*half + mtl)*16 + l15 + v;
                            int unit = sbase + (col>>1)*8 + ((4*(col&1) + lc) ^ ((col>>1)&7));
                            short8 a = *(const short8*)(smem + OFF_P0 + unit*16);
                            if (pr <= 2)
                                acc[mtl*2+0] = __builtin_amdgcn_mfma_f32_16x16x32_bf16(
                                    a, wf[pr*3+v], acc[mtl*2+0], 0, 0, 0);
                            if (pr >= 1)
                                acc[mtl*2+1] = __builtin_amdgcn_mfma_f32_16x16x32_bf16(
                                    a, wf[(pr-1)*3+v], acc[mtl*2+1], 0, 0, 0);
                        }
                    }
                }
                // epilogue for this mt pair: premax -> +bias -> GELU -> P1 ring row i1%6
                #pragma unroll
                for (int mtl = 0; mtl < 2; ++mtl) {
                    int pcol = (2*half + mtl)*8 + lc*2;
                    if (pcol < 30) {
                        f32x4 A0 = acc[mtl*2+0], A1 = acc[mtl*2+1];
                        float p0 = fmaxf(fmaxf(A0[0], A0[1]), fmaxf(A1[0], A1[1]));
                        float p1 = fmaxf(fmaxf(A0[2], A0[3]), fmaxf(A1[2], A1[3]));
                        float m0 = gelu_f(p0 + bias);
                        float m1 = gelu_f(p1 + bias);
                        int u0 = (rbase + pcol)*8     + (xr ^ (pcol & 7));
                        int u1 = (rbase + pcol + 1)*8 + (xr ^ ((pcol+1) & 7));
                        *(unsigned short*)(smem + OFF_P1 + u0*16 + (ch&7)*2) = f2bf(m0);
                        *(unsigned short*)(smem + OFF_P1 + u1*16 + (ch&7)*2) = f2bf(m1);
                    }
                }
            }
        } else if (i1 >= 4 && (i1 & 1) == 0) {
            // ---------- conv2 row i2: waves 4-7, nt=w-4, 2 mtiles ----------
            const int i2 = (i1 - 4) >> 1;
            f32x4 acc[4];   // [mt][row]
            #pragma unroll
            for (int i = 0; i < 4; ++i) acc[i] = (f32x4){0.f,0.f,0.f,0.f};
            #pragma unroll
            for (int pr = 0; pr < 4; ++pr) {
                int rb = ((2*i2 + pr) % 6) * 30;
                #pragma unroll
                for (int v = 0; v < 3; ++v) {
                    #pragma unroll
                    for (int mt = 0; mt < 2; ++mt) {
                        int col = mt*16 + l15 + v;
                        #pragma unroll
                        for (int kh = 0; kh < 2; ++kh) {
                            int unit = (rb + col)*8 + ((kh*4 + lc) ^ (col & 7));
                            short8 a = *(const short8*)(smem + OFF_P1 + unit*16);
                            if (pr <= 2)
                                acc[mt*2+0] = __builtin_amdgcn_mfma_f32_16x16x32_bf16(
                                    a, wf[kh*9 + pr*3+v], acc[mt*2+0], 0, 0, 0);
                            if (pr >= 1)
                                acc[mt*2+1] = __builtin_amdgcn_mfma_f32_16x16x32_bf16(
                                    a, wf[kh*9 + (pr-1)*3+v], acc[mt*2+1], 0, 0, 0);
                        }
                    }
                }
            }
            // epilogue: exact GELU x8 then max -> out
            #pragma unroll
            for (int mt = 0; mt < 2; ++mt) {
                int pcol = mt*8 + lc*2;
                if (pcol < 14) {
                    f32x4 A0 = acc[mt*2+0], A1 = acc[mt*2+1];
                    float g00 = gelu_f(A0[0] + bias), g01 = gelu_f(A0[1] + bias);
                    float g02 = gelu_f(A0[2] + bias), g03 = gelu_f(A0[3] + bias);
                    float g10 = gelu_f(A1[0] + bias), g11 = gelu_f(A1[1] + bias);
                    float g12 = gelu_f(A1[2] + bias), g13 = gelu_f(A1[3] + bias);
                    float m0 = fmaxf(fmaxf(g00, g01), fmaxf(g10, g11));
                    float m1 = fmaxf(fmaxf(g02, g03), fmaxf(g12, g13));
                    float2 st; st.x = m0; st.y = m1;
                    *(float2*)(out + obase + ch*196 + i2*14 + pcol) = st;
                }
            }
        }

        __syncthreads();   // conv1 reads of P0 done; P1 row i1 done
        if (i1 < 29) produce(smem, tys, b0r, c0w, tid, 2*i1 + 4);
    }

    __syncthreads();
    // tail: conv2 row 13 (P1 rows 26..29)
    if (w >= 4) {
        const int i2 = 13;
        f32x4 acc[4];
        #pragma unroll
        for (int i = 0; i < 4; ++i) acc[i] = (f32x4){0.f,0.f,0.f,0.f};
        #pragma unroll
        for (int pr = 0; pr < 4; ++pr) {
            int rb = ((2*i2 + pr) % 6) * 30;
            #pragma unroll
            for (int v = 0; v < 3; ++v) {
                #pragma unroll
                for (int mt = 0; mt < 2; ++mt) {
                    int col = mt*16 + l15 + v;
                    #pragma unroll
                    for (int kh = 0; kh < 2; ++kh) {
                        int unit = (rb + col)*8 + ((kh*4 + lc) ^ (col & 7));
                        short8 a = *(const short8*)(smem + OFF_P1 + unit*16);
                        if (pr <= 2)
                            acc[mt*2+0] = __builtin_amdgcn_mfma_f32_16x16x32_bf16(
                                a, wf[kh*9 + pr*3+v], acc[mt*2+0], 0, 0, 0);
                        if (pr >= 1)
                            acc[mt*2+1] = __builtin_amdgcn_mfma_f32_16x16x32_bf16(
                                a, wf[kh*9 + (pr-1)*3+v], acc[mt*2+1], 0, 0, 0);
                    }
                }
            }
        }
        #pragma unroll
        for (int mt = 0; mt < 2; ++mt) {
            int pcol = mt*8 + lc*2;
            if (pcol < 14) {
                f32x4 A0 = acc[mt*2+0], A1 = acc[mt*2+1];
                float g00 = gelu_f(A0[0] + bias), g01 = gelu_f(A0[1] + bias);
                float g02 = gelu_f(A0[2] + bias), g03 = gelu_f(A0[3] + bias);
                float g10 = gelu_f(A1[0] + bias), g11 = gelu_f(A1[1] + bias);
                float g12 = gelu_f(A1[2] + bias), g13 = gelu_f(A1[3] + bias);
                float m0 = fmaxf(fmaxf(g00, g01), fmaxf(g10, g11));
                float m1 = fmaxf(fmaxf(g02, g03), fmaxf(g12, g13));
                float2 st; st.x = m0; st.y = m1;
                *(float2*)(out + obase + ch*196 + i2*14 + pcol) = st;
            }
        }
    }
}

extern "C" void kernel_launch(void* const* d_in, const int* in_sizes, int n_in,
                              void* d_out, int out_size, void* d_ws, size_t ws_size,
                              hipStream_t stream) {
    const float* token = (const float*)d_in[0];
    const float* type_ = (const float*)d_in[1];
    const float* w0 = (const float*)d_in[2];
    const float* b0 = (const float*)d_in[3];
    const float* w1 = (const float*)d_in[4];
    const float* b1 = (const float*)d_in[5];
    const float* w2 = (const float*)d_in[6];
    const float* b2 = (const float*)d_in[7];
    float* out = (float*)d_out;

    hipLaunchKernelGGL(conv_pipeline, dim3(512), dim3(512), LDS_TOTAL, stream,
                       token, type_, w0, b0, w1, b1, w2, b2, out);
}